// Round 4
// baseline (59.973 us; speedup 1.0000x reference)
//
#include <hip/hip_runtime.h>

// MaxChamferDistance: x[16,4096,3], y[16,4096,3] f32 -> scalar f32
//
// Round-4: round-3 was ds_read_b128-issue-bound (2.1M broadcast reads ~12cyc
// => ~41us of the 49.6us). Changes:
//  - POWN=16 own points/thread; SoA LDS (lq[comp][pt]) read 4 other-points
//    per 4 ds_read_b128 => DS instr count /4 (~10us).
//  - Packed fp32: own points paired into float2, v_pk_fma_f32 via
//    __builtin_elementwise_fma; other-point comps splat (op_sel) => ~2.25
//    VALU lane-ops/pair (~15us).
//  - SEG=32 segments of 128 other-pts (2KB LDS), grid 2048x128 = 4 waves/SIMD.
//  - Cross-segment min via atomicMin on monotone-uint floats (order-indep =>
//    deterministic across replays). ws: 512KB pm + 32 dist floats.

#define BATCH   16
#define NPTS    4096
#define DB      (2 * BATCH)           // 32 (dir,batch) pairs
#define SEG     32
#define SEGPTS  (NPTS / SEG)          // 128
#define THREADS1 128
#define POWN    16
#define PH      (POWN / 2)            // 8 float2 groups
#define CHUNK   (THREADS1 * POWN)     // 2048 own points per block
#define CHUNKS  (NPTS / CHUNK)        // 2
#define NB1     (SEG * DB * CHUNKS)   // 2048 blocks
#define PM_U32  (DB * NPTS)           // 131072 entries = 512 KB

typedef float v2f __attribute__((ext_vector_type(2)));
typedef float v4f __attribute__((ext_vector_type(4)));

__device__ __forceinline__ v2f fma2(v2f a, v2f b, v2f c) {
  return __builtin_elementwise_fma(a, b, c);
}
__device__ __forceinline__ v2f splat2(float v) { return (v2f){v, v}; }

__device__ __forceinline__ unsigned enc_f32(float f) {
  unsigned u = __float_as_uint(f);
  return (u & 0x80000000u) ? ~u : (u | 0x80000000u);   // monotone in f
}
__device__ __forceinline__ float dec_f32(unsigned u) {
  return __uint_as_float((u & 0x80000000u) ? (u ^ 0x80000000u) : ~u);
}

__global__ __launch_bounds__(256) void chamfer_init(unsigned* __restrict__ pm) {
  pm[blockIdx.x * 256 + threadIdx.x] = 0xFFFFFFFFu;    // always overwritten
}

__global__ __launch_bounds__(THREADS1) void chamfer_seg(
    const float* __restrict__ x, const float* __restrict__ y,
    unsigned* __restrict__ pm) {
  __shared__ __align__(16) float lq[4][SEGPTS];  // SoA: (-2p0,-2p1,-2p2,||p||^2)

  const int bid = blockIdx.x;
  const int s   = bid >> 6;            // segment (DB*CHUNKS = 64 blocks each)
  const int rem = bid & 63;
  const int db  = rem >> 1;            // dir*16 + b
  const int c   = rem & 1;             // own-point chunk
  const int dir = db >> 4;
  const int b   = db & 15;

  const float* own   = (dir == 0 ? x : y) + (size_t)b * NPTS * 3;
  const float* other = (dir == 0 ? y : x) + (size_t)b * NPTS * 3;
  const float* sp    = other + (size_t)s * SEGPTS * 3;

  {
    const int i = threadIdx.x;         // THREADS1 == SEGPTS
    float a0 = sp[i * 3 + 0];
    float a1 = sp[i * 3 + 1];
    float a2 = sp[i * 3 + 2];
    lq[0][i] = -2.0f * a0;
    lq[1][i] = -2.0f * a1;
    lq[2][i] = -2.0f * a2;
    lq[3][i] = fmaf(a2, a2, fmaf(a1, a1, a0 * a0));
  }
  __syncthreads();

  // 16 own points per thread, paired into float2 for v_pk_fma_f32
  const int base = c * CHUNK + threadIdx.x;
  v2f x0p[PH], x1p[PH], x2p[PH], sqp[PH], mnp[PH];
  #pragma unroll
  for (int j = 0; j < PH; ++j) {
    const int pa = base + j * (2 * THREADS1);
    const int pb = pa + THREADS1;
    float a0 = own[pa * 3 + 0], a1 = own[pa * 3 + 1], a2 = own[pa * 3 + 2];
    float b0 = own[pb * 3 + 0], b1 = own[pb * 3 + 1], b2 = own[pb * 3 + 2];
    x0p[j] = (v2f){a0, b0};
    x1p[j] = (v2f){a1, b1};
    x2p[j] = (v2f){a2, b2};
    sqp[j] = (v2f){fmaf(a2, a2, fmaf(a1, a1, a0 * a0)),
                   fmaf(b2, b2, fmaf(b1, b1, b0 * b0))};
    mnp[j] = (v2f){1e30f, 1e30f};
  }

  #pragma unroll 2
  for (int m = 0; m < SEGPTS; m += 4) {
    v4f qx = *(const v4f*)&lq[0][m];   // broadcast ds_read_b128 x4 (SoA)
    v4f qy = *(const v4f*)&lq[1][m];
    v4f qz = *(const v4f*)&lq[2][m];
    v4f qw = *(const v4f*)&lq[3][m];
    #pragma unroll
    for (int j = 0; j < PH; ++j) {
      v2f t0 = fma2(x0p[j], splat2(qx.x),
               fma2(x1p[j], splat2(qy.x),
               fma2(x2p[j], splat2(qz.x), splat2(qw.x))));
      v2f t1 = fma2(x0p[j], splat2(qx.y),
               fma2(x1p[j], splat2(qy.y),
               fma2(x2p[j], splat2(qz.y), splat2(qw.y))));
      v2f t2 = fma2(x0p[j], splat2(qx.z),
               fma2(x1p[j], splat2(qy.z),
               fma2(x2p[j], splat2(qz.z), splat2(qw.z))));
      v2f t3 = fma2(x0p[j], splat2(qx.w),
               fma2(x1p[j], splat2(qy.w),
               fma2(x2p[j], splat2(qz.w), splat2(qw.w))));
      mnp[j].x = fminf(fminf(mnp[j].x, fminf(t0.x, t1.x)), fminf(t2.x, t3.x));
      mnp[j].y = fminf(fminf(mnp[j].y, fminf(t0.y, t1.y)), fminf(t2.y, t3.y));
    }
  }

  unsigned* dst = pm + (size_t)db * NPTS;
  #pragma unroll
  for (int j = 0; j < PH; ++j) {
    const int pa = base + j * (2 * THREADS1);
    atomicMin(&dst[pa],            enc_f32(sqp[j].x + mnp[j].x));
    atomicMin(&dst[pa + THREADS1], enc_f32(sqp[j].y + mnp[j].y));
  }
}

__global__ __launch_bounds__(256) void chamfer_combine(
    const unsigned* __restrict__ pm, float* __restrict__ dist) {
  const int db = blockIdx.x;                 // one (dir,b) per block
  const unsigned* q = pm + (size_t)db * NPTS;
  float s = 0.0f;
  #pragma unroll
  for (int i = threadIdx.x; i < NPTS; i += 256)
    s += dec_f32(q[i]);
  #pragma unroll
  for (int off = 32; off > 0; off >>= 1) s += __shfl_down(s, off, 64);
  __shared__ float red[4];
  const int lane = threadIdx.x & 63, wid = threadIdx.x >> 6;
  if (lane == 0) red[wid] = s;
  __syncthreads();
  if (threadIdx.x == 0)
    dist[db] = ((red[0] + red[1]) + (red[2] + red[3])) * (1.0f / (float)NPTS);
}

__global__ void chamfer_final(const float* __restrict__ dist,
                              float* __restrict__ out) {
  if (threadIdx.x == 0) {
    float acc = 0.0f;
    #pragma unroll
    for (int b = 0; b < BATCH; ++b) acc += fmaxf(dist[b], dist[BATCH + b]);
    out[0] = acc * (1.0f / (float)BATCH);
  }
}

extern "C" void kernel_launch(void* const* d_in, const int* in_sizes, int n_in,
                              void* d_out, int out_size, void* d_ws, size_t ws_size,
                              hipStream_t stream) {
  const float* x = (const float*)d_in[0];
  const float* y = (const float*)d_in[1];
  float* out = (float*)d_out;

  unsigned* pm = (unsigned*)d_ws;            // 131072 u32 = 512 KB
  float* dist  = (float*)(pm + PM_U32);      // 32 floats

  chamfer_init<<<PM_U32 / 256, 256, 0, stream>>>(pm);
  chamfer_seg<<<NB1, THREADS1, 0, stream>>>(x, y, pm);
  chamfer_combine<<<DB, 256, 0, stream>>>(pm, dist);
  chamfer_final<<<1, 64, 0, stream>>>(dist, out);
}